// Round 2
// 454.332 us; speedup vs baseline: 1.0143x; 1.0143x over previous
//
#include <hip/hip_runtime.h>

// CrossScan: x (B=16, C=96, H=128, W=128) fp32 -> out (B, 4, C, H*W):
//   s=0: y0[h*W+w] = x[h,w]
//   s=1: y1[w*H+h] = x[h,w]        (HW transpose)
//   s=2: y2[i]     = y0[HW-1-i]    (reverse)
//   s=3: y3[i]     = y1[HW-1-i]
//
// Memory-bound: 96 MiB read + 384 MiB write -> ~80 us floor at 6.3 TB/s.
// All four output streams stored with strictly ASCENDING coalesced float4;
// reversal via flipped LDS reads (reversed image of an aligned 64x64 tile is
// another aligned 64x64 tile with both axes flipped).
//
// R1 change (resubmitted after broker timeout): ALL global traffic
// nontemporal. 5 streams x ~2048 concurrent blocks, zero reuse -> L2/L3
// pollution is pure overhead. NT hint = the streaming-copy idiom. LDS
// scheme deliberately unchanged: +1 pad gives bank (4tx+k+R)%32 -> 2
// lanes/bank (free, m136); any float4-granular LDS layout would make the
// transpose column-reads 8-way conflicted.

typedef float v4f __attribute__((ext_vector_type(4)));

#define Hh 128
#define Ww 128
#define HWp (Hh * Ww)
#define Cc 96
#define Bb 16
#define TILE 64

__global__ __launch_bounds__(256) void cross_scan_kernel(
    const float* __restrict__ x, float* __restrict__ out) {
  // pad +1: row stride 65 = 1 mod 32 -> all access patterns are 2-way (free)
  __shared__ float tile[TILE][TILE + 1];

  const int tx = threadIdx.x;               // 0..15: float4 across 64 cols
  const int ty = threadIdx.y;               // 0..15: row base, rows ty+16j
  const int tileId = blockIdx.x;            // 0..3
  const int r0 = (tileId >> 1) * TILE;      // tile row base (h)
  const int c0 = (tileId & 1) * TILE;       // tile col base (w)
  const int plane = blockIdx.y;             // 0..B*C-1
  const int b = plane / Cc;
  const int c = plane - b * Cc;

  const float* xp = x + (size_t)plane * HWp;
  float* out0 = out + ((size_t)(b * 4 + 0) * Cc + c) * HWp;
  float* out1 = out + ((size_t)(b * 4 + 1) * Cc + c) * HWp;
  float* out2 = out + ((size_t)(b * 4 + 2) * Cc + c) * HWp;
  float* out3 = out + ((size_t)(b * 4 + 3) * Cc + c) * HWp;

  // ---- Phase 1: load 4 float4s (NT), write y0 (NT, ascending), stage tile ----
  v4f v[4];
#pragma unroll
  for (int j = 0; j < 4; ++j) {
    const int r = ty + 16 * j;
    v[j] = __builtin_nontemporal_load(
        (const v4f*)(xp + (r0 + r) * Ww + c0 + tx * 4));
  }
#pragma unroll
  for (int j = 0; j < 4; ++j) {
    const int r = ty + 16 * j;
    __builtin_nontemporal_store(
        v[j], (v4f*)(out0 + (r0 + r) * Ww + c0 + tx * 4));
    tile[r][tx * 4 + 0] = v[j][0];
    tile[r][tx * 4 + 1] = v[j][1];
    tile[r][tx * 4 + 2] = v[j][2];
    tile[r][tx * 4 + 3] = v[j][3];
  }
  __syncthreads();

  // Flipped tile bases in the output image (H=W=128, tiles are 64-aligned):
  const int r2b = TILE - r0;  // y2 out-row base (row flip)
  const int c2b = TILE - c0;  // y2 out-col base (col flip)
  const int R3b = TILE - c0;  // y3 out-row base
  const int c3b = TILE - r0;  // y3 out-col base

  // ---- Phase 2: y1/y2/y3 via LDS, all stores ascending float4 (NT) ----
#pragma unroll
  for (int j = 0; j < 4; ++j) {
    const int R = ty + 16 * j;

    // y1[(c0+R)*W + r0+4tx+k] = x[r0+4tx+k][c0+R] = tile[4tx+k][R]
    v4f t1;
    t1[0] = tile[tx * 4 + 0][R];
    t1[1] = tile[tx * 4 + 1][R];
    t1[2] = tile[tx * 4 + 2][R];
    t1[3] = tile[tx * 4 + 3][R];
    __builtin_nontemporal_store(
        t1, (v4f*)(out1 + (c0 + R) * Hh + r0 + tx * 4));

    // y2[(r2b+R)*W + c2b+4tx+k] = y0[HW-1-that] = tile[63-R][63-4tx-k]
    const float* Trow = &tile[63 - R][0];
    v4f t2;
    t2[0] = Trow[63 - tx * 4];
    t2[1] = Trow[62 - tx * 4];
    t2[2] = Trow[61 - tx * 4];
    t2[3] = Trow[60 - tx * 4];
    __builtin_nontemporal_store(
        t2, (v4f*)(out2 + (r2b + R) * Ww + c2b + tx * 4));

    // y3[(R3b+R)*W + c3b+4tx+k] = y1[HW-1-that] = tile[63-4tx-k][63-R]
    v4f t3;
    t3[0] = tile[63 - tx * 4][63 - R];
    t3[1] = tile[62 - tx * 4][63 - R];
    t3[2] = tile[61 - tx * 4][63 - R];
    t3[3] = tile[60 - tx * 4][63 - R];
    __builtin_nontemporal_store(
        t3, (v4f*)(out3 + (R3b + R) * Hh + c3b + tx * 4));
  }
}

extern "C" void kernel_launch(void* const* d_in, const int* in_sizes, int n_in,
                              void* d_out, int out_size, void* d_ws,
                              size_t ws_size, hipStream_t stream) {
  const float* x = (const float*)d_in[0];
  float* out = (float*)d_out;
  dim3 grid(4, Bb * Cc);  // 4 tiles/plane, 1536 planes
  dim3 block(16, 16);     // 256 threads, 4 waves
  cross_scan_kernel<<<grid, block, 0, stream>>>(x, out);
}